// Round 7
// baseline (409.935 us; speedup 1.0000x reference)
//
#include <hip/hip_runtime.h>
#include <math.h>

#define NPG 1000
#define KTOP 500
#define C 64
#define EPG 16000   // edges per graph = NPG * DEG
#define BPG 63      // gather blocks per graph: ceil(250/4), 4 bases/block, 4 nodes/base-wave

__device__ __forceinline__ int readlane_i(int v, int l) {
    return (int)__builtin_amdgcn_readlane((unsigned)v, (unsigned)l);
}

// ---------------- fused per-graph CSR build: count + scan + scatter in LDS ----------------
// Also zeroes this graph's cen_sum slice (replaces a memset dispatch).
__global__ __launch_bounds__(1024) void build_graph_k(const int* __restrict__ ei, int E,
                                                      int* __restrict__ deg,
                                                      float* __restrict__ dinv,
                                                      int* __restrict__ off,
                                                      int* __restrict__ csr,
                                                      float* __restrict__ cen_sum) {
    int g = blockIdx.x, t = threadIdx.x;
    __shared__ int cnt[NPG];               // counts, then cursors
    __shared__ int soff[NPG];              // local start offsets
    __shared__ unsigned short lcsr[EPG];   // src local ids, dst-grouped
    __shared__ int red[1024];
    const int gbase = g * NPG;
    const int ebase = g * EPG;
    const int* __restrict__ srcp = ei + ebase;
    const int* __restrict__ dstp = ei + E + ebase;

    if (t < C) cen_sum[(size_t)g * C + t] = 0.f;
    for (int i = t; i < NPG; i += 1024) cnt[i] = 0;
    __syncthreads();
    // phase 1: count in-degree (LDS atomics)
    for (int i = t; i < EPG; i += 1024) atomicAdd(&cnt[dstp[i] - gbase], 1);
    __syncthreads();
    // phase 2: exclusive scan over 1000 counts (1/thread, Hillis-Steele on 1024)
    int v = (t < NPG) ? cnt[t] : 0;
    red[t] = v;
    __syncthreads();
    for (int o = 1; o < 1024; o <<= 1) {
        int xx = (t >= o) ? red[t - o] : 0;
        __syncthreads();
        red[t] += xx;
        __syncthreads();
    }
    if (t < NPG) soff[t] = red[t] - v;     // exclusive prefix
    __syncthreads();
    // outputs: deg, dinv, off (coalesced)
    for (int i = t; i < NPG; i += 1024) {
        int d = cnt[i];
        deg[gbase + i] = d;
        dinv[gbase + i] = 1.0f / sqrtf((float)(d + 1));
        off[gbase + i] = ebase + soff[i];
    }
    __syncthreads();
    // reset cursors
    for (int i = t; i < NPG; i += 1024) cnt[i] = soff[i];
    __syncthreads();
    // phase 3: scatter src into dst-grouped order (LDS cursor atomics + LDS writes)
    for (int i = t; i < EPG; i += 1024) {
        int d = dstp[i] - gbase;
        int pos = atomicAdd(&cnt[d], 1);
        lcsr[pos] = (unsigned short)(srcp[i] - gbase);
    }
    __syncthreads();
    // phase 4: dump csr as coalesced int4 stores (EPG % 4 == 0)
    int4* co = (int4*)(csr + ebase);
    for (int i = t; i < EPG / 4; i += 1024) {
        int4 vv;
        vv.x = gbase + (int)lcsr[i * 4 + 0];
        vv.y = gbase + (int)lcsr[i * 4 + 1];
        vv.z = gbase + (int)lcsr[i * 4 + 2];
        vv.w = gbase + (int)lcsr[i * 4 + 3];
        co[i] = vv;
    }
}

// ---------------- h2 = (x @ W) * dinv[row] : tiled GEMM, 8x8 register tile --------------
// 128 threads/block, 128 rows x 64 cols per block. x-tile staged COALESCED from global
// and stored transposed xT[k][row] (pad 132 -> 2-way banks, free). W row-major in LDS.
// Per k-step: 4 ds_read_b128 feed 64 FMAs (vs old 8:1 ratio and uncoalesced x reads).
__global__ __launch_bounds__(128) void gemm_k(const float* __restrict__ x,
                                              const float* __restrict__ W,
                                              const float* __restrict__ dinv,
                                              float* __restrict__ h2, int N) {
    __shared__ float xT[64][132];          // 33.8 KB, transposed x tile
    __shared__ float sW[C * C];            // 16.4 KB
    int t = threadIdx.x;
    int rbase = blockIdx.x * 128;          // N % 128 == 0
    if (rbase >= N) return;
    // stage W (coalesced float4)
    for (int i = t; i < C * C / 4; i += 128) ((float4*)sW)[i] = ((const float4*)W)[i];
    // stage x tile: 2048 float4, coalesced read, transposed scatter to LDS
    const float4* xsrc = (const float4*)(x + (size_t)rbase * C);
    for (int i = t; i < 2048; i += 128) {
        float4 v = xsrc[i];
        int r = i >> 4;                    // float4 i covers row i/16 ...
        int k0 = (i & 15) * 4;             // ... cols 4*(i%16)..+3
        xT[k0 + 0][r] = v.x;
        xT[k0 + 1][r] = v.y;
        xT[k0 + 2][r] = v.z;
        xT[k0 + 3][r] = v.w;
    }
    __syncthreads();
    int rg = t >> 3;                       // 16 row-groups
    int cg = t & 7;                        // 8 col-groups
    int r0 = rg * 8;
    int c0 = cg * 8;
    float acc[8][8];
#pragma unroll
    for (int i = 0; i < 8; ++i)
#pragma unroll
        for (int j = 0; j < 8; ++j) acc[i][j] = 0.f;
    for (int k = 0; k < 64; ++k) {
        float4 a0 = *(const float4*)&xT[k][r0];
        float4 a1 = *(const float4*)&xT[k][r0 + 4];
        float4 b0 = *(const float4*)&sW[k * C + c0];
        float4 b1 = *(const float4*)&sW[k * C + c0 + 4];
        float av[8] = { a0.x, a0.y, a0.z, a0.w, a1.x, a1.y, a1.z, a1.w };
        float bv[8] = { b0.x, b0.y, b0.z, b0.w, b1.x, b1.y, b1.z, b1.w };
#pragma unroll
        for (int i = 0; i < 8; ++i)
#pragma unroll
            for (int j = 0; j < 8; ++j)
                acc[i][j] = fmaf(av[i], bv[j], acc[i][j]);
    }
    // epilogue: scale rows by dinv, store (8 threads/row -> 256B contiguous)
    float dv[8];
#pragma unroll
    for (int i = 0; i < 8; ++i) dv[i] = dinv[rbase + r0 + i];
#pragma unroll
    for (int i = 0; i < 8; ++i) {
        float4 o0, o1;
        o0.x = acc[i][0] * dv[i]; o0.y = acc[i][1] * dv[i];
        o0.z = acc[i][2] * dv[i]; o0.w = acc[i][3] * dv[i];
        o1.x = acc[i][4] * dv[i]; o1.y = acc[i][5] * dv[i];
        o1.z = acc[i][6] * dv[i]; o1.w = acc[i][7] * dv[i];
        float4* dst = (float4*)(h2 + (size_t)(rbase + r0 + i) * C + c0);
        dst[0] = o0;
        dst[1] = o1;
    }
}

// ---------------- gather aggregation: 4 nodes per wave, lane = channel (unchanged) ------
__global__ __launch_bounds__(256) void gather_k(const int* __restrict__ csr,
                                                const int* __restrict__ off,
                                                const int* __restrict__ deg,
                                                const float* __restrict__ h2,
                                                const float* __restrict__ dinv,
                                                const float* __restrict__ bias,
                                                float* __restrict__ out2,
                                                float* __restrict__ cen_sum,
                                                int N, int B) {
    __shared__ float cenacc[C];
    int blk = blockIdx.x;
    int wave = threadIdx.x >> 6;
    int lane = threadIdx.x & 63;
    int t = threadIdx.x;
    int g, blkin;
    if ((B & 7) == 0) {                    // XCD swizzle: whole graph on one XCD
        int xcd = blk & 7, slot = blk >> 3;
        g = (slot / BPG) * 8 + xcd;
        blkin = slot % BPG;
    } else {
        g = blk / BPG;
        blkin = blk % BPG;
    }
    if (t < C) cenacc[t] = 0.f;
    __syncthreads();

    int base = blkin * 4 + wave;
    bool active = (base < NPG / 4);
    if (active) {
        int nA = g * NPG + base;
        int nB = nA + 250, nC = nA + 500, nD = nA + 750;
        int oA = off[nA], oB = off[nB], oC = off[nC], oD = off[nD];
        int dA = deg[nA], dB = deg[nB], dC = deg[nC], dD = deg[nD];
        float diA = dinv[nA], diB = dinv[nB], diC = dinv[nC], diD = dinv[nD];
        float hA = h2[(size_t)nA * C + lane];
        float hB = h2[(size_t)nB * C + lane];
        float hC = h2[(size_t)nC * C + lane];
        float hD = h2[(size_t)nD * C + lane];
        float bv = bias[lane];
        int svA = (lane < dA) ? csr[oA + lane] : nA;
        int svB = (lane < dB) ? csr[oB + lane] : nB;
        int svC = (lane < dC) ? csr[oC + lane] : nC;
        int svD = (lane < dD) ? csr[oD + lane] : nD;
        int jmA = dA < 64 ? dA : 64;
        int jmB = dB < 64 ? dB : 64;
        int jmC = dC < 64 ? dC : 64;
        int jmD = dD < 64 ? dD : 64;
        int rA = (jmA + 3) & ~3, rB = (jmB + 3) & ~3;
        int rC = (jmC + 3) & ~3, rD = (jmD + 3) & ~3;
        int m0 = rA > rB ? rA : rB;
        int m1 = rC > rD ? rC : rD;
        int mmax = m0 > m1 ? m0 : m1;
        float aA = 0.f, aB = 0.f, aC = 0.f, aD = 0.f;
        for (int j = 0; j < mmax; j += 4) {
            if (j < rA) {
                int s0 = readlane_i(svA, j + 0), s1 = readlane_i(svA, j + 1);
                int s2 = readlane_i(svA, j + 2), s3 = readlane_i(svA, j + 3);
                float v0 = h2[(size_t)s0 * C + lane];
                float v1 = h2[(size_t)s1 * C + lane];
                float v2 = h2[(size_t)s2 * C + lane];
                float v3 = h2[(size_t)s3 * C + lane];
                aA += (v0 + v1) + (v2 + v3);
            }
            if (j < rB) {
                int s0 = readlane_i(svB, j + 0), s1 = readlane_i(svB, j + 1);
                int s2 = readlane_i(svB, j + 2), s3 = readlane_i(svB, j + 3);
                float v0 = h2[(size_t)s0 * C + lane];
                float v1 = h2[(size_t)s1 * C + lane];
                float v2 = h2[(size_t)s2 * C + lane];
                float v3 = h2[(size_t)s3 * C + lane];
                aB += (v0 + v1) + (v2 + v3);
            }
            if (j < rC) {
                int s0 = readlane_i(svC, j + 0), s1 = readlane_i(svC, j + 1);
                int s2 = readlane_i(svC, j + 2), s3 = readlane_i(svC, j + 3);
                float v0 = h2[(size_t)s0 * C + lane];
                float v1 = h2[(size_t)s1 * C + lane];
                float v2 = h2[(size_t)s2 * C + lane];
                float v3 = h2[(size_t)s3 * C + lane];
                aC += (v0 + v1) + (v2 + v3);
            }
            if (j < rD) {
                int s0 = readlane_i(svD, j + 0), s1 = readlane_i(svD, j + 1);
                int s2 = readlane_i(svD, j + 2), s3 = readlane_i(svD, j + 3);
                float v0 = h2[(size_t)s0 * C + lane];
                float v1 = h2[(size_t)s1 * C + lane];
                float v2 = h2[(size_t)s2 * C + lane];
                float v3 = h2[(size_t)s3 * C + lane];
                aD += (v0 + v1) + (v2 + v3);
            }
        }
        for (int j = 64; j < dA; ++j) aA += h2[(size_t)csr[oA + j] * C + lane];
        for (int j = 64; j < dB; ++j) aB += h2[(size_t)csr[oB + j] * C + lane];
        for (int j = 64; j < dC; ++j) aC += h2[(size_t)csr[oC + j] * C + lane];
        for (int j = 64; j < dD; ++j) aD += h2[(size_t)csr[oD + j] * C + lane];
        float cA = 1.0f - (float)(rA - jmA);
        float cB = 1.0f - (float)(rB - jmB);
        float cC = 1.0f - (float)(rC - jmC);
        float cD = 1.0f - (float)(rD - jmD);
        float resA = fmaf(diA, fmaf(cA, hA, aA), bv);
        float resB = fmaf(diB, fmaf(cB, hB, aB), bv);
        float resC = fmaf(diC, fmaf(cC, hC, aC), bv);
        float resD = fmaf(diD, fmaf(cD, hD, aD), bv);
        out2[(size_t)nA * C + lane] = resA;
        out2[(size_t)nB * C + lane] = resB;
        out2[(size_t)nC * C + lane] = resC;
        out2[(size_t)nD * C + lane] = resD;
        float csum = (resA + resB) + (resC + resD);
        atomicAdd(&cenacc[lane], csum);
    }
    __syncthreads();
    if (t < C) atomicAdd(&cen_sum[(size_t)g * C + t], cenacc[t]);
}

// ---------------- score: device-wide, wave per 4 rows; cen/cnorm derived inline ----------
__global__ __launch_bounds__(256) void score2_k(const float* __restrict__ out2,
                                                const float* __restrict__ cen_sum,
                                                float* __restrict__ score, int N) {
    int wave = threadIdx.x >> 6, lane = threadIdx.x & 63;
    int r0 = blockIdx.x * 16 + wave * 4;          // 4 rows per wave
    if (r0 >= N) return;
    int g0 = (r0 + 0) / NPG, g1 = (r0 + 1) / NPG;
    int g2 = (r0 + 2) / NPG, g3 = (r0 + 3) / NPG;
    const float inv = 1.0f / 1000.0f;
    float m0 = cen_sum[(size_t)g0 * C + lane] * inv;
    float m1 = cen_sum[(size_t)g1 * C + lane] * inv;
    float m2 = cen_sum[(size_t)g2 * C + lane] * inv;
    float m3 = cen_sum[(size_t)g3 * C + lane] * inv;
    float a0 = out2[(size_t)(r0 + 0) * C + lane];
    float a1 = out2[(size_t)(r0 + 1) * C + lane];
    float a2 = out2[(size_t)(r0 + 2) * C + lane];
    float a3 = out2[(size_t)(r0 + 3) * C + lane];
    float n0 = a0 * m0, n1 = a1 * m1, n2 = a2 * m2, n3 = a3 * m3;
    float q0 = a0 * a0, q1 = a1 * a1, q2 = a2 * a2, q3 = a3 * a3;
    float c0 = m0 * m0, c1 = m1 * m1, c2 = m2 * m2, c3 = m3 * m3;
    for (int o = 32; o > 0; o >>= 1) {
        n0 += __shfl_down(n0, o, 64); q0 += __shfl_down(q0, o, 64); c0 += __shfl_down(c0, o, 64);
        n1 += __shfl_down(n1, o, 64); q1 += __shfl_down(q1, o, 64); c1 += __shfl_down(c1, o, 64);
        n2 += __shfl_down(n2, o, 64); q2 += __shfl_down(q2, o, 64); c2 += __shfl_down(c2, o, 64);
        n3 += __shfl_down(n3, o, 64); q3 += __shfl_down(q3, o, 64); c3 += __shfl_down(c3, o, 64);
    }
    if (lane == 0) {
        score[r0 + 0] = n0 / (sqrtf(q0) * sqrtf(c0) + 1e-8f);
        score[r0 + 1] = n1 / (sqrtf(q1) * sqrtf(c1) + 1e-8f);
        score[r0 + 2] = n2 / (sqrtf(q2) * sqrtf(c2) + 1e-8f);
        score[r0 + 3] = n3 / (sqrtf(q3) * sqrtf(c3) + 1e-8f);
    }
}

// ---------------- per-graph tail: softmax-KL + bitonic argsort + top-K + x_new ----------
__global__ __launch_bounds__(1024) void post2_k(const float* __restrict__ score,
                                                const float* __restrict__ out2,
                                                int* __restrict__ mapping,
                                                float* __restrict__ o_xnew,
                                                float* __restrict__ o_batch,
                                                float* __restrict__ o_perm,
                                                float* __restrict__ o_kl,
                                                float* __restrict__ o_ind) {
    __shared__ float ss[NPG];
    __shared__ float red[1024];
    __shared__ unsigned long long kk[1024];
    __shared__ int   map[NPG];
    int g = blockIdx.x, t = threadIdx.x;
    int wave = t >> 6, lane = t & 63;
    const int gbase = g * NPG;

    // stage score row (coalesced float4)
    const float4* s4 = (const float4*)(score + (size_t)gbase);
    if (t < NPG / 4) ((float4*)ss)[t] = s4[t];
    __syncthreads();
    // softmax KL vs uniform
    float mx = -INFINITY;
    if (t < NPG) mx = ss[t];
    red[t] = mx;
    __syncthreads();
    for (int w = 512; w > 0; w >>= 1) { if (t < w) red[t] = fmaxf(red[t], red[t + w]); __syncthreads(); }
    mx = red[0];
    __syncthreads();
    float se = (t < NPG) ? expf(ss[t] - mx) : 0.f;
    red[t] = se;
    __syncthreads();
    for (int w = 512; w > 0; w >>= 1) { if (t < w) red[t] += red[t + w]; __syncthreads(); }
    float lse = logf(red[0]);
    __syncthreads();
    const float ln_npg = 6.9077552790f;
    float kl = 0.f;
    if (t < NPG) {
        float lp = ss[t] - mx - lse;
        kl = expf(lp) * (lp + ln_npg);
    }
    red[t] = kl;
    __syncthreads();
    for (int w = 512; w > 0; w >>= 1) { if (t < w) red[t] += red[t + w]; __syncthreads(); }
    if (t == 0) o_kl[g] = red[0];
    // descending stable argsort via ascending (~flipped_score, idx) bitonic
    unsigned long long v;
    if (t < NPG) {
        unsigned u = __float_as_uint(ss[t]);
        u = (u & 0x80000000u) ? ~u : (u | 0x80000000u);
        v = ((unsigned long long)(~u) << 32) | (unsigned)t;
    } else {
        v = ~0ULL;
    }
    __syncthreads();
    kk[t] = v;
    __syncthreads();
    for (int k = 2; k <= 1024; k <<= 1) {
        for (int j = k >> 1; j > 0; j >>= 1) {
            int ixj = t ^ j;
            if (ixj > t) {
                unsigned long long a = kk[t], b2 = kk[ixj];
                bool up = ((t & k) == 0);
                if ((a > b2) == up) { kk[t] = b2; kk[ixj] = a; }
            }
            __syncthreads();
        }
    }
    // indices output + mapping init
    if (t < NPG) {
        int idx = (int)(kk[t] & 0xFFFFFFFFULL);
        o_ind[(size_t)g * NPG + t] = (float)idx;
        map[t] = -1;
    }
    __syncthreads();
    // top-K bookkeeping
    if (t < KTOP) {
        int node = (int)(kk[t] & 0xFFFFFFFFULL);
        map[node] = g * KTOP + t;
        o_perm[(size_t)g * KTOP + t] = (float)(gbase + node);
        o_batch[(size_t)g * KTOP + t] = (float)g;
    }
    __syncthreads();
    // mapping -> global (coalesced)
    if (t < NPG) mapping[gbase + t] = map[t];
    // x_new rows: wave per row (coalesced 256B read+write)
    for (int r = wave; r < KTOP; r += 16) {
        int node = (int)(kk[r] & 0xFFFFFFFFULL);
        float tn = tanhf(ss[node]);
        o_xnew[((size_t)g * KTOP + r) * C + lane] =
            out2[(size_t)(gbase + node) * C + lane] * tn;
    }
}

// ---------------- edge re-index + mask + attr (device-wide, x4 vectorized) ----------------
__global__ void edge_out_k(const int* __restrict__ ei, const float* __restrict__ eattr,
                           const int* __restrict__ mapping, float* __restrict__ o_newei,
                           float* __restrict__ o_eattr, float* __restrict__ o_mask, int E) {
    int e4 = blockIdx.x * 256 + threadIdx.x;
    int q = E >> 2;
    if (e4 < q) {
        int4 sidx = ((const int4*)ei)[e4];
        int4 didx = ((const int4*)ei)[q + e4];
        int a0 = mapping[sidx.x], a1 = mapping[sidx.y], a2 = mapping[sidx.z], a3 = mapping[sidx.w];
        int b0 = mapping[didx.x], b1 = mapping[didx.y], b2 = mapping[didx.z], b3 = mapping[didx.w];
        float4 f0 = { (float)a0, (float)a1, (float)a2, (float)a3 };
        float4 f1 = { (float)b0, (float)b1, (float)b2, (float)b3 };
        ((float4*)o_newei)[e4] = f0;
        ((float4*)o_newei)[q + e4] = f1;
        float4 at = ((const float4*)eattr)[e4];
        float4 mk, ea;
        mk.x = (a0 >= 0 && b0 >= 0) ? 1.0f : 0.0f;
        mk.y = (a1 >= 0 && b1 >= 0) ? 1.0f : 0.0f;
        mk.z = (a2 >= 0 && b2 >= 0) ? 1.0f : 0.0f;
        mk.w = (a3 >= 0 && b3 >= 0) ? 1.0f : 0.0f;
        ea.x = mk.x != 0.0f ? at.x : 0.0f;
        ea.y = mk.y != 0.0f ? at.y : 0.0f;
        ea.z = mk.z != 0.0f ? at.z : 0.0f;
        ea.w = mk.w != 0.0f ? at.w : 0.0f;
        ((float4*)o_mask)[e4] = mk;
        ((float4*)o_eattr)[e4] = ea;
    }
}

extern "C" void kernel_launch(void* const* d_in, const int* in_sizes, int n_in,
                              void* d_out, int out_size, void* d_ws, size_t ws_size,
                              hipStream_t stream) {
    (void)n_in; (void)out_size; (void)ws_size;
    const float* x     = (const float*)d_in[1];
    const int*   ei    = (const int*)d_in[2];
    const float* eattr = (const float*)d_in[3];
    const float* W     = (const float*)d_in[5];
    const float* bias  = (const float*)d_in[6];

    const int N  = in_sizes[1] / C;    // 256000
    const int E  = in_sizes[2] / 2;    // 4096000
    const int B  = N / NPG;            // 256
    const int BK = B * KTOP;           // 128000

    // workspace layout
    char* wsp = (char*)d_ws;
    float* out2    = (float*)wsp; wsp += (size_t)N * C * 4;   // 65.5 MB
    float* dinv    = (float*)wsp; wsp += (size_t)N * 4;
    int*   deg     = (int*)wsp;   wsp += (size_t)N * 4;
    int*   off     = (int*)wsp;   wsp += (size_t)N * 4;
    int*   mapping = (int*)wsp;   wsp += (size_t)N * 4;
    float* score   = (float*)wsp; wsp += (size_t)N * 4;
    float* cen_sum = (float*)wsp; wsp += (size_t)B * C * 4;

    // output layout (flat f32, reference return order)
    float* out     = (float*)d_out;
    float* o_xnew  = out;                                   // BK*C
    float* o_newei = o_xnew + (size_t)BK * C;               // 2E
    float* o_eattr = o_newei + 2 * (size_t)E;               // E
    float* o_mask  = o_eattr + (size_t)E;                   // E
    float* o_batch = o_mask + (size_t)E;                    // BK
    float* o_perm  = o_batch + (size_t)BK;                  // BK
    float* o_kl    = o_perm + (size_t)BK;                   // B
    float* o_ind   = o_kl + (size_t)B;                      // B*NPG

    // scratch aliased onto d_out (dead before those outputs are written)
    float* h2buf = out;                // N*C floats (= o_xnew + o_newei region)
    int*   csr   = (int*)o_eattr;      // E ints

    build_graph_k<<<B, 1024, 0, stream>>>(ei, E, deg, dinv, off, csr, cen_sum);
    gemm_k<<<N / 128, 128, 0, stream>>>(x, W, dinv, h2buf, N);
    gather_k<<<B * BPG, 256, 0, stream>>>(csr, off, deg, h2buf, dinv, bias, out2,
                                          cen_sum, N, B);
    score2_k<<<(N + 15) / 16, 256, 0, stream>>>(out2, cen_sum, score, N);
    post2_k<<<B, 1024, 0, stream>>>(score, out2, mapping,
                                    o_xnew, o_batch, o_perm, o_kl, o_ind);
    edge_out_k<<<(E / 4 + 255) / 256, 256, 0, stream>>>(ei, eattr, mapping,
                                                        o_newei, o_eattr, o_mask, E);
}